// Round 7
// baseline (296.803 us; speedup 1.0000x reference)
//
#include <hip/hip_runtime.h>
#include <math.h>

#define TINYF 1.17549435e-38f
#define TINYD 1.1754943508222875e-38  // float32 tiny, exact

namespace {
constexpr int kB = 8, kD = 256, kC = 1024, kR = 64, kO = 256;
constexpr int kS = kB * kC;  // 8192 samples
// workspace byte offsets
constexpr size_t OFF_G1B  = 0;        // float [D][R] inv_s2
constexpr size_t OFF_G2B  = 65536;    // float [D][R] c*inv_s2
constexpr size_t OFF_G3B  = 131072;   // float [R]
constexpr size_t OFF_IMPB = 131584;   // double [R]
constexpr size_t OFF_NTB  = 132096;   // float [R][S]  (2 MB)
constexpr size_t OFF_WBB  = OFF_NTB + (size_t)kR * kS * 4;       // bf16 W copy
constexpr size_t WS_NEED  = OFF_WBB + (size_t)kR * kO * kD * 2;  // ~10.6 MB
}  // namespace

typedef float f32x4 __attribute__((ext_vector_type(4)));
typedef short short8 __attribute__((ext_vector_type(8)));

__device__ __forceinline__ short f2bf(float f) {  // f32 -> bf16 bits, RNE
  unsigned u = __builtin_bit_cast(unsigned, f);
  unsigned r = ((u >> 16) & 1u) + 0x7fffu;
  return (short)((u + r) >> 16);
}
__device__ __forceinline__ unsigned pk(short a, short b) {
  return (unsigned)(unsigned short)a | ((unsigned)(unsigned short)b << 16);
}

// numpy pairwise_sum order for n=64 f32 (8 strided accumulators + fixed tree).
__device__ __forceinline__ float np_sum64(const float* __restrict__ a) {
#pragma clang fp contract(off)
  float r0 = a[0], r1 = a[1], r2 = a[2], r3 = a[3];
  float r4 = a[4], r5 = a[5], r6 = a[6], r7 = a[7];
  for (int i = 8; i < 64; i += 8) {
    r0 += a[i + 0]; r1 += a[i + 1]; r2 += a[i + 2]; r3 += a[i + 3];
    r4 += a[i + 4]; r5 += a[i + 5]; r6 += a[i + 6]; r7 += a[i + 7];
  }
  return ((r0 + r1) + (r2 + r3)) + ((r4 + r5) + (r6 + r7));
}

// ---------------- prep: g1/g2 + g3 (numpy pairwise-256 exact, parallelized)
__global__ __launch_bounds__(256) void prep_kernel(const float* __restrict__ center,
                                                   const float* __restrict__ sigma,
                                                   float* __restrict__ g1,
                                                   float* __restrict__ g2,
                                                   float* __restrict__ g3) {
#pragma clang fp contract(off)
  int r = blockIdx.x;   // 64
  int d = threadIdx.x;  // 256 == D
  float sg = sigma[r * kD + d] + TINYF;
  float is2 = 1.0f / (sg * sg);
  float cn = center[r * kD + d];
  g1[(size_t)d * kR + r] = is2;
  g2[(size_t)d * kR + r] = cn * is2;
  __shared__ float tl[256];
  __shared__ float pp[16];
  tl[d] = (cn * cn) * is2;
  __syncthreads();
  if (d < 16) {  // np pairwise(256) = pw(128)+pw(128); 8 strided accs each, in order
    int h = d >> 3, j = d & 7;
    const float* base = tl + h * 128 + j;
    float a = base[0];
    for (int i = 1; i < 16; ++i) a = a + base[i * 8];
    pp[d] = a;
  }
  __syncthreads();
  if (d == 0) {
    float h0 = ((pp[0] + pp[1]) + (pp[2] + pp[3])) + ((pp[4] + pp[5]) + (pp[6] + pp[7]));
    float h1 = ((pp[8] + pp[9]) + (pp[10] + pp[11])) + ((pp[12] + pp[13]) + (pp[14] + pp[15]));
    g3[r] = h0 + h1;
  }
}

// ---- norm: numpy-f32-bit-replicated distances, softmax, top-p, renorm
// + fused imp accumulation (f64 atomics; f64 makes ordering irrelevant).
__global__ __launch_bounds__(256) void norm_kernel(const float* __restrict__ x,
                                                   const float* __restrict__ g1,
                                                   const float* __restrict__ g2,
                                                   const float* __restrict__ g3,
                                                   float* __restrict__ nt,
                                                   double* __restrict__ impd,
                                                   float tauf) {
#pragma clang fp contract(off)
  __shared__ float buf[4][64];
  __shared__ float nfb[4][64];
  __shared__ float sb[4][64];
  __shared__ float bc[4];
  __shared__ double impl[4][64];
  int w = threadIdx.x >> 6;
  int lane = threadIdx.x & 63;
  int s0 = blockIdx.x * 16 + w * 4;
  int b = s0 >> 10;
  int c0 = s0 & (kC - 1);
  const float* xb = x + (size_t)b * kD * kC + c0;
  float e1[4] = {0.f, 0.f, 0.f, 0.f}, e2[4] = {0.f, 0.f, 0.f, 0.f};
  for (int d = 0; d < kD; ++d) {
    float a1 = g1[(size_t)d * kR + lane];
    float a2 = g2[(size_t)d * kR + lane];
    float4 xv = *(const float4*)(xb + (size_t)d * kC);
    float xs[4] = {xv.x, xv.y, xv.z, xv.w};
    for (int q = 0; q < 4; ++q) {
      float xx = xs[q] * xs[q];
      e1[q] = e1[q] + xx * a1;
      e2[q] = e2[q] + xs[q] * a2;
    }
  }
  float g3v = g3[lane];
  double impacc = 0.0;
#pragma unroll 1
  for (int q = 0; q < 4; ++q) {
    float sqf = (e1[q] - 2.0f * e2[q]) + g3v;
    float argf = sqf * -0.001953125f;
    float firef = (float)exp((double)argf) + TINYF;
    buf[w][lane] = firef;
    __syncthreads();
    float ssum = np_sum64(buf[w]);
    float normf = firef / (ssum + TINYF);
    nfb[w][lane] = normf;
    __syncthreads();
    int rank = 0;
    for (int j = 0; j < 64; ++j) {
      float vj = nfb[w][j];
      rank += (vj > normf) || (vj == normf && j < lane);
    }
    sb[w][rank] = normf;
    __syncthreads();
    if (lane == 0) {
      float cs = 0.f, beste = 1e30f;
      int bidx = 0;
      for (int i = 0; i < 64; ++i) {
        cs = cs + sb[w][i];
        float e = cs - tauf;
        if (e < 0.f) e = 1.0f;
        if (e < beste) { beste = e; bidx = i; }
      }
      bc[w] = sb[w][bidx];
    }
    __syncthreads();
    float vals = bc[w];
    float masked = (normf >= vals) ? normf : 0.f;
    buf[w][lane] = masked;
    __syncthreads();
    float s2 = np_sum64(buf[w]);
    float ov = masked / (s2 + TINYF);
    nt[(size_t)lane * kS + s0 + q] = ov;
    impacc += (double)ov;
    __syncthreads();
  }
  impl[w][lane] = impacc;
  __syncthreads();
  if (threadIdx.x < 64) {
    double v = impl[0][threadIdx.x] + impl[1][threadIdx.x] + impl[2][threadIdx.x] +
               impl[3][threadIdx.x];
    atomicAdd(&impd[threadIdx.x], v);
  }
}

// ---------------------------------------------------------------- loss (f64)
__global__ __launch_bounds__(64) void loss_kernel(const double* __restrict__ impd,
                                                  float* __restrict__ out) {
  int t = threadIdx.x;
  double v = impd[t];
  double sum = v;
#pragma unroll
  for (int off = 32; off; off >>= 1) sum += __shfl_xor(sum, off, 64);
  double mean = sum * (1.0 / 64.0);
  double dv = v - mean;
  double ss = dv * dv;
#pragma unroll
  for (int off = 32; off; off >>= 1) ss += __shfl_xor(ss, off, 64);
  double var = ss * (1.0 / 63.0);
  if (t == 0) out[(size_t)kS * kO] = (float)(0.01 * (var / (mean * mean + 1e-20)));
}

// ----------------------------------------------- W f32 -> bf16 copy (preconv)
__global__ __launch_bounds__(256) void wcvt_kernel(const float* __restrict__ Wm,
                                                   short* __restrict__ Wb) {
  size_t i = ((size_t)blockIdx.x * 256 + threadIdx.x) * 4;
  float4 v = *(const float4*)(Wm + i);
  uint2 p;
  p.x = pk(f2bf(v.x), f2bf(v.y));
  p.y = pk(f2bf(v.z), f2bf(v.w));
  *(uint2*)(Wb + i) = p;
}

// fallback staging: f32 W -> bf16 swizzled LDS tile [2r][16o][128k]
__device__ __forceinline__ void stage_f32(short* dst, const float* __restrict__ Wm,
                                          int r0, int h, int o0, int tid) {
  int g = tid >> 3, sp0 = (tid & 7) * 2;  // g: row 0..31, 2 slots of 16B each
  const float* src = Wm + ((size_t)((r0 + (g >> 4)) * kO) + o0 + (g & 15)) * kD +
                     h * 128 + sp0 * 8;
#pragma unroll
  for (int s = 0; s < 2; ++s) {
    float4 v0 = *(const float4*)(src + s * 8);
    float4 v1 = *(const float4*)(src + s * 8 + 4);
    uint4 p;
    p.x = pk(f2bf(v0.x), f2bf(v0.y));
    p.y = pk(f2bf(v0.z), f2bf(v0.w));
    p.z = pk(f2bf(v1.x), f2bf(v1.y));
    p.w = pk(f2bf(v1.z), f2bf(v1.w));
    int slot = (sp0 + s) ^ (g & 7);
    *(uint4*)((char*)dst + g * 256 + slot * 16) = p;
  }
}

// ------------------- pred: bf16-MFMA cons GEMM + f32 norm contraction + bias
// grid 512: o_t=bid&15 (16 o-slices; 2 per XCD, 1MB bf16 W L2-resident),
// s_t=bid>>4. Block = 256s x 16o, 4 waves of 64s x 16o (f=4, q=1: each W
// b128 read feeds 4 MFMAs). 64 iters x {2 rules, one 128k half}; double-
// buffered LDS tile [2r][16o][128k] XOR-swizzled; raw s_barrier + counted
// vmcnt(10/8); setprio around MFMA cluster.
template <int PRECONV>
__global__ __launch_bounds__(256, 2) void pred_kernel(
    const float* __restrict__ x, const float* __restrict__ Wm,
    const short* __restrict__ Wb, const float* __restrict__ bias,
    const float* __restrict__ nt, float* __restrict__ out) {
  __shared__ __align__(16) short w_smem[2][4096];   // 2 x 8 KB
  __shared__ __align__(16) float bias_smem[kR * 16];  // 4 KB
  const int tid = threadIdx.x;
  const int w = tid >> 6, l = tid & 63;
  const int bid = blockIdx.x;
  const int o0 = (bid & 15) * 16;
  const int s_t = bid >> 4;  // 0..31
  const int b = s_t >> 2;
  const int c0 = (s_t & 3) * 256;
  const int cw = c0 + w * 64;
  const float* xb = x + (size_t)b * kD * kC + cw;
  const int l15 = l & 15, lh = l >> 4;
  // ---- bias -> LDS
  for (int i = tid; i < kR * 16; i += 256)
    bias_smem[i] = bias[(i >> 4) * kO + o0 + (i & 15)];
  // ---- x fragments, half 0
  short8 a[4][4];
#pragma unroll
  for (int f = 0; f < 4; ++f)
#pragma unroll
    for (int kk = 0; kk < 4; ++kk) {
      const float* xp = xb + (size_t)(kk * 32 + lh * 8) * kC + f * 16 + l15;
      short8 v;
#pragma unroll
      for (int j = 0; j < 8; ++j) v[j] = f2bf(xp[(size_t)j * kC]);
      a[f][kk] = v;
    }
  const int snorm = s_t * 256 + w * 64 + lh * 4;  // + f*16
  // ---- norm prefetch for t=0 (r=0,1)
  f32x4 nA[4], nB[4], nA2[4], nB2[4];
#pragma unroll
  for (int f = 0; f < 4; ++f) {
    nA[f] = *(const f32x4*)(nt + snorm + f * 16);
    nB[f] = *(const f32x4*)(nt + kS + snorm + f * 16);
    nA2[f] = (f32x4){0, 0, 0, 0};
    nB2[f] = (f32x4){0, 0, 0, 0};
  }
  // ---- stage tile 0 (h=0, r=0,1)
  if constexpr (PRECONV) {
#pragma unroll
    for (int i = 0; i < 2; ++i) {
      int g = (w * 2 + i) * 4 + lh;
      int blk = l15 ^ (g & 7);
      const char* src =
          (const char*)Wb + ((size_t)((g >> 4) * kO) + o0 + (g & 15)) * 512 + blk * 16;
      __builtin_amdgcn_global_load_lds(
          (const __attribute__((address_space(1))) void*)src,
          (__attribute__((address_space(3))) void*)((char*)&w_smem[0][0] +
                                                    (w * 2 + i) * 1024),
          16, 0, 0);
    }
    asm volatile("s_waitcnt vmcnt(0)" ::: "memory");
  } else {
    stage_f32(&w_smem[0][0], Wm, 0, 0, o0, tid);
  }
  __syncthreads();

  f32x4 acc[4];
#pragma unroll
  for (int f = 0; f < 4; ++f) acc[f] = (f32x4){0, 0, 0, 0};
  float4 wreg[4];  // fallback prefetch regs

  int cur = 0;
  for (int t = 0; t < 64; ++t) {
    const int h = t >> 5, r0 = (t & 31) * 2;
    if constexpr (PRECONV) {
      asm volatile("s_barrier" ::: "memory");  // A: buf[cur^1] readers done
      if (t < 63) {
        int tn = t + 1, hn = tn >> 5, rn0 = (tn & 31) * 2;
        char* dst = (char*)&w_smem[cur ^ 1][0];
#pragma unroll
        for (int i = 0; i < 2; ++i) {
          int g = (w * 2 + i) * 4 + lh;
          int blk = l15 ^ (g & 7);
          const char* src = (const char*)Wb +
                            ((size_t)((rn0 + (g >> 4)) * kO) + o0 + (g & 15)) * 512 +
                            hn * 256 + blk * 16;
          __builtin_amdgcn_global_load_lds(
              (const __attribute__((address_space(1))) void*)src,
              (__attribute__((address_space(3))) void*)(dst + (w * 2 + i) * 1024), 16, 0,
              0);
        }
        // outstanding (oldest first): stage(t)[2], L_t[8], stage(t+1)[2]
        asm volatile("s_waitcnt vmcnt(10)" ::: "memory");  // drain stage(t) only
      } else {
        asm volatile("s_waitcnt vmcnt(8)" ::: "memory");
      }
      asm volatile("s_barrier" ::: "memory");  // B: buf[cur] fully staged
    } else {
      __syncthreads();
      if (t < 63) {  // prefetch next f32 tile (this thread's 2 slots)
        int tn = t + 1, hn = tn >> 5, rn0 = (tn & 31) * 2;
        int g = tid >> 3, sp0 = (tid & 7) * 2;
        const float* src = Wm + ((size_t)((rn0 + (g >> 4)) * kO) + o0 + (g & 15)) * kD +
                           hn * 128 + sp0 * 8;
#pragma unroll
        for (int i = 0; i < 4; ++i) wreg[i] = *(const float4*)(src + i * 4);
      }
    }
    // ---- half-1 x fragments (once)
    if (t == 32) {
#pragma unroll
      for (int f = 0; f < 4; ++f)
#pragma unroll
        for (int kk = 0; kk < 4; ++kk) {
          const float* xp = xb + (size_t)(128 + kk * 32 + lh * 8) * kC + f * 16 + l15;
          short8 v;
#pragma unroll
          for (int j = 0; j < 8; ++j) v[j] = f2bf(xp[(size_t)j * kC]);
          a[f][kk] = v;
        }
    }
    // ---- compute 2 rules from buf[cur]
    const char* wbuf = (const char*)&w_smem[cur][0];
#pragma unroll
    for (int rl = 0; rl < 2; ++rl) {
      f32x4 cons[4];
#pragma unroll
      for (int f = 0; f < 4; ++f) cons[f] = (f32x4){0, 0, 0, 0};
      __builtin_amdgcn_s_setprio(1);
#pragma unroll
      for (int kk = 0; kk < 4; ++kk) {
        short8 bfr = *(const short8*)(wbuf + rl * 4096 + l15 * 256 +
                                      ((kk * 64 + (lh << 4)) ^ ((l & 7) << 4)));
#pragma unroll
        for (int f = 0; f < 4; ++f)
          cons[f] = __builtin_amdgcn_mfma_f32_16x16x32_bf16(a[f][kk], bfr, cons[f], 0, 0, 0);
      }
      __builtin_amdgcn_s_setprio(0);
      float bv = (h == 1) ? bias_smem[(r0 + rl) * 16 + l15] : 0.f;
      const f32x4* nn = rl ? nB : nA;
#pragma unroll
      for (int f = 0; f < 4; ++f)
#pragma unroll
        for (int e = 0; e < 4; ++e) acc[f][e] += nn[f][e] * (cons[f][e] + bv);
    }
    // ---- norm prefetch for t+1 (issued before next stage -> older; compiler
    // waits with counted vmcnt, stage(t+2) stays in flight)
    if (t < 63) {
      int rn0 = ((t + 1) & 31) * 2;
#pragma unroll
      for (int f = 0; f < 4; ++f) {
        nA2[f] = *(const f32x4*)(nt + (size_t)rn0 * kS + snorm + f * 16);
        nB2[f] = *(const f32x4*)(nt + (size_t)(rn0 + 1) * kS + snorm + f * 16);
      }
    }
    if constexpr (!PRECONV) {
      __syncthreads();
      if (t < 63) {
        int g = tid >> 3, sp0 = (tid & 7) * 2;
        char* dstb = (char*)&w_smem[cur ^ 1][0];
#pragma unroll
        for (int s = 0; s < 2; ++s) {
          uint4 p;
          p.x = pk(f2bf(wreg[s * 2].x), f2bf(wreg[s * 2].y));
          p.y = pk(f2bf(wreg[s * 2].z), f2bf(wreg[s * 2].w));
          p.z = pk(f2bf(wreg[s * 2 + 1].x), f2bf(wreg[s * 2 + 1].y));
          p.w = pk(f2bf(wreg[s * 2 + 1].z), f2bf(wreg[s * 2 + 1].w));
          int slot = (sp0 + s) ^ (g & 7);
          *(uint4*)(dstb + g * 256 + slot * 16) = p;
        }
      }
    }
#pragma unroll
    for (int f = 0; f < 4; ++f) { nA[f] = nA2[f]; nB[f] = nB2[f]; }
    cur ^= 1;
  }
  // ---- store: out[b][o][c]; D col = o (l&15), rows = c (lh*4+e)
#pragma unroll
  for (int f = 0; f < 4; ++f) {
    int o_abs = o0 + l15;
    int c_abs = cw + f * 16 + lh * 4;
    *(f32x4*)(out + (size_t)b * (kO * kC) + (size_t)o_abs * kC + c_abs) = acc[f];
  }
}

extern "C" void kernel_launch(void* const* d_in, const int* in_sizes, int n_in,
                              void* d_out, int out_size, void* d_ws, size_t ws_size,
                              hipStream_t stream) {
  const float* x = (const float*)d_in[0];
  const float* center = (const float*)d_in[1];
  const float* sigma = (const float*)d_in[2];
  const float* Wm = (const float*)d_in[3];
  const float* bias = (const float*)d_in[4];
  float* out = (float*)d_out;
  char* wsb = (char*)d_ws;
  float* g1 = (float*)(wsb + OFF_G1B);
  float* g2 = (float*)(wsb + OFF_G2B);
  float* g3 = (float*)(wsb + OFF_G3B);
  double* impd = (double*)(wsb + OFF_IMPB);
  float* nt = (float*)(wsb + OFF_NTB);
  short* Wb = (short*)(wsb + OFF_WBB);
  double tau = 0.9 * pow(1.0 / (64.0 + TINYD), 1.0 / 256.0);
  float tauf = (float)tau;
  bool preconv = (ws_size >= WS_NEED);
  hipMemsetAsync((void*)impd, 0, kR * sizeof(double), stream);
  prep_kernel<<<kR, 256, 0, stream>>>(center, sigma, g1, g2, g3);
  if (preconv) wcvt_kernel<<<(kR * kO * kD) / 1024, 256, 0, stream>>>(Wm, Wb);
  norm_kernel<<<kS / 16, 256, 0, stream>>>(x, g1, g2, g3, nt, impd, tauf);
  if (preconv) {
    pred_kernel<1><<<512, 256, 0, stream>>>(x, Wm, Wb, bias, nt, out);
  } else {
    pred_kernel<0><<<512, 256, 0, stream>>>(x, Wm, Wb, bias, nt, out);
  }
  loss_kernel<<<1, 64, 0, stream>>>(impd, out);
}

// Round 9
// 272.293 us; speedup vs baseline: 1.0900x; 1.0900x over previous
//
#include <hip/hip_runtime.h>
#include <math.h>

#define TINYF 1.17549435e-38f
#define TINYD 1.1754943508222875e-38  // float32 tiny, exact

namespace {
constexpr int kB = 8, kD = 256, kC = 1024, kR = 64, kO = 256;
constexpr int kS = kB * kC;  // 8192 samples
// workspace byte offsets
constexpr size_t OFF_G1B  = 0;        // float [D][R] inv_s2
constexpr size_t OFF_G2B  = 65536;    // float [D][R] c*inv_s2
constexpr size_t OFF_G3B  = 131072;   // float [R]
constexpr size_t OFF_IMPB = 131584;   // double [R]
constexpr size_t OFF_NTB  = 132096;   // float [R][S]  (2 MB)
constexpr size_t OFF_WBB  = OFF_NTB + (size_t)kR * kS * 4;       // bf16 W copy
constexpr size_t WS_NEED  = OFF_WBB + (size_t)kR * kO * kD * 2;  // ~10.6 MB
}  // namespace

typedef float f32x4 __attribute__((ext_vector_type(4)));
typedef short short8 __attribute__((ext_vector_type(8)));

__device__ __forceinline__ short f2bf(float f) {  // f32 -> bf16 bits, RNE
  unsigned u = __builtin_bit_cast(unsigned, f);
  unsigned r = ((u >> 16) & 1u) + 0x7fffu;
  return (short)((u + r) >> 16);
}
__device__ __forceinline__ unsigned pk(short a, short b) {
  return (unsigned)(unsigned short)a | ((unsigned)(unsigned short)b << 16);
}

// numpy pairwise_sum order for n=64 f32 (8 strided accumulators + fixed tree).
__device__ __forceinline__ float np_sum64(const float* __restrict__ a) {
#pragma clang fp contract(off)
  float r0 = a[0], r1 = a[1], r2 = a[2], r3 = a[3];
  float r4 = a[4], r5 = a[5], r6 = a[6], r7 = a[7];
  for (int i = 8; i < 64; i += 8) {
    r0 += a[i + 0]; r1 += a[i + 1]; r2 += a[i + 2]; r3 += a[i + 3];
    r4 += a[i + 4]; r5 += a[i + 5]; r6 += a[i + 6]; r7 += a[i + 7];
  }
  return ((r0 + r1) + (r2 + r3)) + ((r4 + r5) + (r6 + r7));
}

// ---------------- prep: g1/g2 + g3 (numpy pairwise-256 exact, parallelized)
__global__ __launch_bounds__(256) void prep_kernel(const float* __restrict__ center,
                                                   const float* __restrict__ sigma,
                                                   float* __restrict__ g1,
                                                   float* __restrict__ g2,
                                                   float* __restrict__ g3) {
#pragma clang fp contract(off)
  int r = blockIdx.x;   // 64
  int d = threadIdx.x;  // 256 == D
  float sg = sigma[r * kD + d] + TINYF;
  float is2 = 1.0f / (sg * sg);
  float cn = center[r * kD + d];
  g1[(size_t)d * kR + r] = is2;
  g2[(size_t)d * kR + r] = cn * is2;
  __shared__ float tl[256];
  __shared__ float pp[16];
  tl[d] = (cn * cn) * is2;
  __syncthreads();
  if (d < 16) {  // np pairwise(256)=pw(128)+pw(128); 8 strided accs each, in order
    int h = d >> 3, j = d & 7;
    const float* base = tl + h * 128 + j;
    float a = base[0];
    for (int i = 1; i < 16; ++i) a = a + base[i * 8];
    pp[d] = a;
  }
  __syncthreads();
  if (d == 0) {
    float h0 = ((pp[0] + pp[1]) + (pp[2] + pp[3])) + ((pp[4] + pp[5]) + (pp[6] + pp[7]));
    float h1 = ((pp[8] + pp[9]) + (pp[10] + pp[11])) + ((pp[12] + pp[13]) + (pp[14] + pp[15]));
    g3[r] = h0 + h1;
  }
}

// ---- norm: numpy-f32-bit-replicated distances, softmax, top-p, renorm
// + fused imp accumulation (f64 atomics; f64 makes ordering irrelevant).
__global__ __launch_bounds__(256) void norm_kernel(const float* __restrict__ x,
                                                   const float* __restrict__ g1,
                                                   const float* __restrict__ g2,
                                                   const float* __restrict__ g3,
                                                   float* __restrict__ nt,
                                                   double* __restrict__ impd,
                                                   float tauf) {
#pragma clang fp contract(off)
  __shared__ float buf[4][64];
  __shared__ float nfb[4][64];
  __shared__ float sb[4][64];
  __shared__ float bc[4];
  __shared__ double impl[4][64];
  int w = threadIdx.x >> 6;
  int lane = threadIdx.x & 63;
  int s0 = blockIdx.x * 16 + w * 4;
  int b = s0 >> 10;
  int c0 = s0 & (kC - 1);
  const float* xb = x + (size_t)b * kD * kC + c0;
  float e1[4] = {0.f, 0.f, 0.f, 0.f}, e2[4] = {0.f, 0.f, 0.f, 0.f};
  for (int d = 0; d < kD; ++d) {
    float a1 = g1[(size_t)d * kR + lane];
    float a2 = g2[(size_t)d * kR + lane];
    float4 xv = *(const float4*)(xb + (size_t)d * kC);
    float xs[4] = {xv.x, xv.y, xv.z, xv.w};
    for (int q = 0; q < 4; ++q) {
      float xx = xs[q] * xs[q];
      e1[q] = e1[q] + xx * a1;
      e2[q] = e2[q] + xs[q] * a2;
    }
  }
  float g3v = g3[lane];
  double impacc = 0.0;
#pragma unroll 1
  for (int q = 0; q < 4; ++q) {
    float sqf = (e1[q] - 2.0f * e2[q]) + g3v;
    float argf = sqf * -0.001953125f;
    float firef = (float)exp((double)argf) + TINYF;
    buf[w][lane] = firef;
    __syncthreads();
    float ssum = np_sum64(buf[w]);
    float normf = firef / (ssum + TINYF);
    nfb[w][lane] = normf;
    __syncthreads();
    int rank = 0;
    for (int j = 0; j < 64; ++j) {
      float vj = nfb[w][j];
      rank += (vj > normf) || (vj == normf && j < lane);
    }
    sb[w][rank] = normf;
    __syncthreads();
    if (lane == 0) {
      float cs = 0.f, beste = 1e30f;
      int bidx = 0;
      for (int i = 0; i < 64; ++i) {
        cs = cs + sb[w][i];
        float e = cs - tauf;
        if (e < 0.f) e = 1.0f;
        if (e < beste) { beste = e; bidx = i; }
      }
      bc[w] = sb[w][bidx];
    }
    __syncthreads();
    float vals = bc[w];
    float masked = (normf >= vals) ? normf : 0.f;
    buf[w][lane] = masked;
    __syncthreads();
    float s2 = np_sum64(buf[w]);
    float ov = masked / (s2 + TINYF);
    nt[(size_t)lane * kS + s0 + q] = ov;
    impacc += (double)ov;
    __syncthreads();
  }
  impl[w][lane] = impacc;
  __syncthreads();
  if (threadIdx.x < 64) {
    double v = impl[0][threadIdx.x] + impl[1][threadIdx.x] + impl[2][threadIdx.x] +
               impl[3][threadIdx.x];
    atomicAdd(&impd[threadIdx.x], v);
  }
}

// ---------------------------------------------------------------- loss (f64)
__global__ __launch_bounds__(64) void loss_kernel(const double* __restrict__ impd,
                                                  float* __restrict__ out) {
  int t = threadIdx.x;
  double v = impd[t];
  double sum = v;
#pragma unroll
  for (int off = 32; off; off >>= 1) sum += __shfl_xor(sum, off, 64);
  double mean = sum * (1.0 / 64.0);
  double dv = v - mean;
  double ss = dv * dv;
#pragma unroll
  for (int off = 32; off; off >>= 1) ss += __shfl_xor(ss, off, 64);
  double var = ss * (1.0 / 63.0);
  if (t == 0) out[(size_t)kS * kO] = (float)(0.01 * (var / (mean * mean + 1e-20)));
}

// ----------------------------------------------- W f32 -> bf16 copy (preconv)
__global__ __launch_bounds__(256) void wcvt_kernel(const float* __restrict__ Wm,
                                                   short* __restrict__ Wb) {
  size_t i = ((size_t)blockIdx.x * 256 + threadIdx.x) * 4;
  float4 v = *(const float4*)(Wm + i);
  uint2 p;
  p.x = pk(f2bf(v.x), f2bf(v.y));
  p.y = pk(f2bf(v.z), f2bf(v.w));
  *(uint2*)(Wb + i) = p;
}

// ------------------- pred: bf16-MFMA cons GEMM + f32 norm contraction + bias
// grid 512: o_t=bid>>5 (16 o-slices), s_t=bid&31 -> per-XCD x/nt slice is
// L2-resident, W streams. Block = 256s x 16o, 4 waves of 64s x 16o (f=4, q=1).
// 32 iters x {4 rules, one 128k half}; W bf16 tiles [4r][16o][128k] 16 KB,
// XOR-swizzled, TRIPLE-buffered via global_load_lds (stage t+2 each iter);
// raw s_barrier + derived vmcnt(24/20/16); norm prefetched at top-of-iter.
// amdgpu_waves_per_eu(2,2): pin 2 blocks/CU, VGPR budget 256 (r7 spilled @128).
template <int PRECONV>
__global__ __launch_bounds__(256) __attribute__((amdgpu_waves_per_eu(2, 2)))
void pred_kernel(const float* __restrict__ x, const float* __restrict__ Wm,
                 const short* __restrict__ Wb, const float* __restrict__ bias,
                 const float* __restrict__ nt, float* __restrict__ out) {
  __shared__ __align__(16) short w_smem[3][8192];     // 3 x 16 KB
  __shared__ __align__(16) float bias_smem[kR * 16];  // 4 KB
  const int tid = threadIdx.x;
  const int w = tid >> 6, l = tid & 63;
  const int bid = blockIdx.x;
  const int o0 = (bid >> 5) * 16;
  const int s_t = bid & 31;
  const int b = s_t >> 2;
  const int c0 = (s_t & 3) * 256;
  const int cw = c0 + w * 64;
  const float* xb = x + (size_t)b * kD * kC + cw;
  const int l15 = l & 15, lh = l >> 4;
  const int snorm = s_t * 256 + w * 64 + lh * 4;

  // ---- bias -> LDS
  for (int i = tid; i < kR * 16; i += 256)
    bias_smem[i] = bias[(i >> 4) * kO + o0 + (i & 15)];

  // ---- x fragments (wave's 64 s x 128 k half) -> registers
  short8 a[4][4];
  auto load_a = [&](int hh) {
#pragma unroll
    for (int f = 0; f < 4; ++f)
#pragma unroll
      for (int kk = 0; kk < 4; ++kk) {
        const float* xp = xb + (size_t)(hh * 128 + kk * 32 + lh * 8) * kC + f * 16 + l15;
        short8 v;
#pragma unroll
        for (int j = 0; j < 8; ++j) v[j] = f2bf(xp[(size_t)j * kC]);
        a[f][kk] = v;
      }
  };
  load_a(0);

  // ---- staging lambdas
  auto stage_tile = [&](int tt, int bufidx) {  // PRECONV: wave w stages rl=w rows
    int hh = tt >> 4, rr0 = (tt & 15) * 4;
    char* dst = (char*)w_smem + bufidx * 16384 + w * 4096;
    const char* srow =
        (const char*)Wb + ((size_t)((rr0 + w) * kO) + o0) * 512 + hh * 256;
#pragma unroll
    for (int i = 0; i < 4; ++i) {
      int o_l = i * 4 + lh;                 // row-in-tile (g = w*16 + o_l)
      int blk = l15 ^ (o_l & 7);            // inverse-swizzled global source
      const char* src = srow + (size_t)o_l * 512 + blk * 16;
      __builtin_amdgcn_global_load_lds(
          (const __attribute__((address_space(1))) void*)src,
          (__attribute__((address_space(3))) void*)(dst + i * 1024), 16, 0, 0);
    }
  };
  auto stage_f32t = [&](int tt, int bufidx) {  // fallback: reg-stage + convert
    int hh = tt >> 4, rr0 = (tt & 15) * 4;
    int g = tid >> 2, j = tid & 3;
    const float* srow =
        Wm + ((size_t)((rr0 + (g >> 4)) * kO) + o0 + (g & 15)) * kD + hh * 128;
    char* dst = (char*)w_smem + bufidx * 16384 + g * 256;
#pragma unroll
    for (int i = 0; i < 4; ++i) {
      int d = j * 4 + i;
      int lam = d ^ (g & 7);
      float4 v0 = *(const float4*)(srow + lam * 8);
      float4 v1 = *(const float4*)(srow + lam * 8 + 4);
      uint4 p;
      p.x = pk(f2bf(v0.x), f2bf(v0.y));
      p.y = pk(f2bf(v0.z), f2bf(v0.w));
      p.z = pk(f2bf(v1.x), f2bf(v1.y));
      p.w = pk(f2bf(v1.z), f2bf(v1.w));
      *(uint4*)(dst + d * 16) = p;
    }
  };

  f32x4 acc[4];
#pragma unroll
  for (int f = 0; f < 4; ++f) acc[f] = (f32x4){0, 0, 0, 0};

  if constexpr (PRECONV) {  // prologue: tiles 0,1 in flight
    stage_tile(0, 0);
    stage_tile(1, 1);
  }

  int bc_ = 0, bn_ = 2;  // compute buf, stage-dest buf (mod-3 rotation)
  for (int t = 0; t < 32; ++t) {
    const int h = t >> 4, r0 = (t & 15) * 4;
    f32x4 nn[4][4];
    if constexpr (PRECONV) {
      asm volatile("s_barrier" ::: "memory");  // A: readers of overwrite-buf done
      // norm prefetch FIRST (older than stage(t+2): its consumption this iter
      // never drains the new stage)
#pragma unroll
      for (int rl = 0; rl < 4; ++rl)
#pragma unroll
        for (int f = 0; f < 4; ++f)
          nn[rl][f] = *(const f32x4*)(nt + (size_t)(r0 + rl) * kS + snorm + f * 16);
      if (t < 30) stage_tile(t + 2, bn_);
      // derived: steady outstanding younger-than-stage(t) =
      // stage(t+1)[4] + norm(t)[16] + stage(t+2)[4] = 24
      if (t < 30) {
        asm volatile("s_waitcnt vmcnt(24)" ::: "memory");
      } else if (t == 30) {
        asm volatile("s_waitcnt vmcnt(20)" ::: "memory");
      } else {
        asm volatile("s_waitcnt vmcnt(16)" ::: "memory");
      }
      __builtin_amdgcn_sched_barrier(0);
      asm volatile("s_barrier" ::: "memory");  // B: tile t staged by ALL waves
    } else {
      __syncthreads();
      stage_f32t(t, t & 1);
#pragma unroll
      for (int rl = 0; rl < 4; ++rl)
#pragma unroll
        for (int f = 0; f < 4; ++f)
          nn[rl][f] = *(const f32x4*)(nt + (size_t)(r0 + rl) * kS + snorm + f * 16);
      __syncthreads();
    }
    if (t == 16) load_a(1);  // half switch (one-time pipeline hiccup, OK)
    const char* wbuf =
        (const char*)w_smem + (PRECONV ? bc_ : (t & 1)) * 16384;
#pragma unroll
    for (int rl = 0; rl < 4; ++rl) {
      f32x4 cons[4];
#pragma unroll
      for (int f = 0; f < 4; ++f) cons[f] = (f32x4){0, 0, 0, 0};
      __builtin_amdgcn_s_setprio(1);
#pragma unroll
      for (int kk = 0; kk < 4; ++kk) {
        short8 bfr = *(const short8*)(wbuf + (rl * 16 + l15) * 256 +
                                      ((kk * 64 + (lh << 4)) ^ ((l15 & 7) << 4)));
#pragma unroll
        for (int f = 0; f < 4; ++f)
          cons[f] = __builtin_amdgcn_mfma_f32_16x16x32_bf16(a[f][kk], bfr, cons[f], 0, 0, 0);
      }
      __builtin_amdgcn_s_setprio(0);
      float bv = (h == 1) ? bias_smem[(r0 + rl) * 16 + l15] : 0.f;
#pragma unroll
      for (int f = 0; f < 4; ++f)
#pragma unroll
        for (int e = 0; e < 4; ++e) acc[f][e] += nn[rl][f][e] * (cons[f][e] + bv);
    }
    bc_ = (bc_ == 2) ? 0 : bc_ + 1;
    bn_ = (bn_ == 2) ? 0 : bn_ + 1;
  }
  // ---- store: out[b][o][c]; D col = o (l15), rows = c (lh*4+e)
#pragma unroll
  for (int f = 0; f < 4; ++f) {
    int o_abs = o0 + l15;
    int c_abs = cw + f * 16 + lh * 4;
    *(f32x4*)(out + (size_t)b * (kO * kC) + (size_t)o_abs * kC + c_abs) = acc[f];
  }
}

extern "C" void kernel_launch(void* const* d_in, const int* in_sizes, int n_in,
                              void* d_out, int out_size, void* d_ws, size_t ws_size,
                              hipStream_t stream) {
  const float* x = (const float*)d_in[0];
  const float* center = (const float*)d_in[1];
  const float* sigma = (const float*)d_in[2];
  const float* Wm = (const float*)d_in[3];
  const float* bias = (const float*)d_in[4];
  float* out = (float*)d_out;
  char* wsb = (char*)d_ws;
  float* g1 = (float*)(wsb + OFF_G1B);
  float* g2 = (float*)(wsb + OFF_G2B);
  float* g3 = (float*)(wsb + OFF_G3B);
  double* impd = (double*)(wsb + OFF_IMPB);
  float* nt = (float*)(wsb + OFF_NTB);
  short* Wb = (short*)(wsb + OFF_WBB);
  double tau = 0.9 * pow(1.0 / (64.0 + TINYD), 1.0 / 256.0);
  float tauf = (float)tau;
  bool preconv = (ws_size >= WS_NEED);
  hipMemsetAsync((void*)impd, 0, kR * sizeof(double), stream);
  prep_kernel<<<kR, 256, 0, stream>>>(center, sigma, g1, g2, g3);
  if (preconv) wcvt_kernel<<<(kR * kO * kD) / 1024, 256, 0, stream>>>(Wm, Wb);
  norm_kernel<<<kS / 16, 256, 0, stream>>>(x, g1, g2, g3, nt, impd, tauf);
  if (preconv) {
    pred_kernel<1><<<512, 256, 0, stream>>>(x, Wm, Wb, bias, nt, out);
  } else {
    pred_kernel<0><<<512, 256, 0, stream>>>(x, Wm, Wb, bias, nt, out);
  }
  loss_kernel<<<1, 64, 0, stream>>>(impd, out);
}